// Round 1
// baseline (148.222 us; speedup 1.0000x reference)
//
#include <hip/hip_runtime.h>
#include <cstddef>

#define TDIM 1024
#define SEQ 8192
#define NROWS 4096

__global__ __launch_bounds__(256) void hist_kernel(const int* __restrict__ his,
                                                   int* __restrict__ counts) {
    __shared__ int lc[TDIM];
    const int tid = threadIdx.x;
    for (int t = tid; t < TDIM; t += 256) lc[t] = 0;
    __syncthreads();
    const int base = blockIdx.x * 1024;  // 8 blocks x 1024 entries = 8192
    for (int i = tid; i < 1024; i += 256) {
        int h = his[base + i];
        atomicAdd(&lc[h], 1);
    }
    __syncthreads();
    for (int t = tid; t < TDIM; t += 256) {
        int c = lc[t];
        if (c) atomicAdd(&counts[t], c);
    }
}

__global__ __launch_bounds__(256) void softmax_gather_kernel(
    const int* __restrict__ his, const int* __restrict__ cur,
    const float* __restrict__ M, const int* __restrict__ counts,
    float* __restrict__ out)
{
    __shared__ float prob[TDIM];
    __shared__ float red[16];
    const int tid = threadIdx.x;
    const int row = blockIdx.x;
    const int r = cur[row];                  // wave-uniform broadcast load
    const float* Mrow = M + (size_t)r * TDIM;

    float m[4];
    int   c[4];
#pragma unroll
    for (int k = 0; k < 4; ++k) {
        int t = tid + 256 * k;
        m[k] = Mrow[t];
        c[k] = counts[t];
    }

    // --- masked block max over the 1024 table columns actually present in his ---
    float lmax = -3.402823466e38f;
#pragma unroll
    for (int k = 0; k < 4; ++k)
        if (c[k] > 0) lmax = fmaxf(lmax, m[k]);
#pragma unroll
    for (int off = 32; off > 0; off >>= 1)
        lmax = fmaxf(lmax, __shfl_down(lmax, off, 64));
    const int wave = tid >> 6, lane = tid & 63;
    if (lane == 0) red[wave] = lmax;
    __syncthreads();
    if (tid == 0) {
        float g = red[0];
        for (int w = 1; w < 4; ++w) g = fmaxf(g, red[w]);
        red[8] = g;
    }
    __syncthreads();
    const float gmax = red[8];

    // --- histogram-weighted exp sum:  sum = sum_t c[t] * exp(M[r][t] - max) ---
    float e[4];
    float lsum = 0.f;
#pragma unroll
    for (int k = 0; k < 4; ++k) {
        e[k] = __expf(m[k] - gmax);
        lsum += (float)c[k] * e[k];
    }
#pragma unroll
    for (int off = 32; off > 0; off >>= 1)
        lsum += __shfl_down(lsum, off, 64);
    if (lane == 0) red[4 + wave] = lsum;   // distinct slots; red[8] already consumed
    __syncthreads();
    if (tid == 0) {
        float s = red[4] + red[5] + red[6] + red[7];
        red[9] = 1.0f / s;
    }
    __syncthreads();
    const float inv = red[9];

    // --- normalized prob table into LDS (entries with c==0 are never read) ---
#pragma unroll
    for (int k = 0; k < 4; ++k)
        prob[tid + 256 * k] = e[k] * inv;
    __syncthreads();

    // --- pure gather + coalesced float4 write: out[row][j] = prob[his[j]] ---
    const int4* his4 = (const int4*)his;                       // 2048 int4
    float4* out4 = (float4*)(out + (size_t)row * SEQ);
#pragma unroll
    for (int it = 0; it < 8; ++it) {
        int j4 = it * 256 + tid;
        int4 h = his4[j4];
        float4 o;
        o.x = prob[h.x];
        o.y = prob[h.y];
        o.z = prob[h.z];
        o.w = prob[h.w];
        out4[j4] = o;
    }
}

extern "C" void kernel_launch(void* const* d_in, const int* in_sizes, int n_in,
                              void* d_out, int out_size, void* d_ws, size_t ws_size,
                              hipStream_t stream) {
    const int*   his = (const int*)d_in[0];    // (8192,) int32 in [0,1024)
    const int*   cur = (const int*)d_in[1];    // (4096,) int32 in [0,1024)
    const float* M   = (const float*)d_in[2];  // (1024,1024) fp32
    float* out = (float*)d_out;                // (4096,8192) fp32
    int* counts = (int*)d_ws;                  // 4 KB scratch

    hipMemsetAsync(counts, 0, TDIM * sizeof(int), stream);
    hist_kernel<<<8, 256, 0, stream>>>(his, counts);
    softmax_gather_kernel<<<NROWS, 256, 0, stream>>>(his, cur, M, counts, out);
}